// Round 6
// baseline (6202.824 us; speedup 1.0000x reference)
//
#include <hip/hip_runtime.h>

// LSTM: B=128, S=256, I=512, H=1024, O=512.
// R6: 256 blocks x 256 thr. block = (rq = blockIdx>>6: 32 batch rows,
// cg = blockIdx&63: 64 gate-cols). wave = (ct = w&1 col-tile, kh = w>>1
// K-half of each 128-chunk); cross-kh reduce via LDS in epilogue.
// A operand (x pre-barrier cached, h post-barrier) loaded to REGISTERS in one
// coalesced burst per step, dripped into a 4-slot LDS pipeline; B (Wc) cached
// 2-deep pipeline. 12 chunks of K=128 (0..3 = x, 4..11 = h).
// h exchange: producers always store UC (relaxed agent atomics, write-through
// to fabric/MALL); consumers use ROTATING buffers (one per step) so normal
// CACHED loads are cold-miss-correct (never-cached addresses), full L2 bw --
// falls back to UC reads + 2-buffer ping-pong if ws_size is too small.
// Sync: distributed-slot barrier per rq-group (64 slots), relaxed atomics,
// no fences (agent fences = whole-L2 wbl2/inv, measured disaster in R3).
// Deadlock-free: 256 blocks, 1/CU (64 KB LDS, <=2 fit), all co-resident.

#define B_ 128
#define S_ 256
#define I_ 512
#define H_ 1024
#define O_ 512

typedef unsigned short u16;
typedef unsigned int u32;
typedef unsigned long long u64;

typedef short v8s __attribute__((ext_vector_type(8)));
typedef float v16f __attribute__((ext_vector_type(16)));
typedef float v4f __attribute__((ext_vector_type(4)));

struct BSet { uint4 b[4]; };

__device__ __forceinline__ u16 f2bf(float f) {
  u32 u = __float_as_uint(f);
  u32 r = (u + 0x7fffu + ((u >> 16) & 1u)) >> 16;   // RNE
  return (u16)r;
}
__device__ __forceinline__ u32 pack2(float a, float b) {
  return (u32)f2bf(a) | ((u32)f2bf(b) << 16);
}
__device__ __forceinline__ uint4 cvt8(const float* __restrict__ s) {
  float4 f0 = ((const float4*)s)[0];
  float4 f1 = ((const float4*)s)[1];
  uint4 o;
  o.x = pack2(f0.x, f0.y); o.y = pack2(f0.z, f0.w);
  o.z = pack2(f1.x, f1.y); o.w = pack2(f1.z, f1.w);
  return o;
}

__device__ __forceinline__ uint4 uc_ld16(const u16* p) {
  u64 lo = __hip_atomic_load((const u64*)p, __ATOMIC_RELAXED, __HIP_MEMORY_SCOPE_AGENT);
  u64 hi = __hip_atomic_load((const u64*)p + 1, __ATOMIC_RELAXED, __HIP_MEMORY_SCOPE_AGENT);
  uint4 v; v.x = (u32)lo; v.y = (u32)(lo >> 32); v.z = (u32)hi; v.w = (u32)(hi >> 32);
  return v;
}
__device__ __forceinline__ void uc_st16(u16* p, uint4 v) {
  u64 lo = (u64)v.x | ((u64)v.y << 32);
  u64 hi = (u64)v.z | ((u64)v.w << 32);
  __hip_atomic_store((u64*)p, lo, __ATOMIC_RELAXED, __HIP_MEMORY_SCOPE_AGENT);
  __hip_atomic_store((u64*)p + 1, hi, __ATOMIC_RELAXED, __HIP_MEMORY_SCOPE_AGENT);
}

// ---------------------------------------------------------------- prep ----
__global__ void lstm_prep(
    const float* __restrict__ x,
    const float* __restrict__ Whf, const float* __restrict__ Whi,
    const float* __restrict__ Whg, const float* __restrict__ Who,
    const float* __restrict__ Wxf, const float* __restrict__ Wxi,
    const float* __restrict__ Wxg, const float* __restrict__ Wxo,
    const float* __restrict__ bfp, const float* __restrict__ bip,
    const float* __restrict__ bgp, const float* __restrict__ bop,
    const float* __restrict__ Why,
    u16* __restrict__ xt, u16* __restrict__ Wc, float* __restrict__ bc,
    u16* __restrict__ WhyT, u16* __restrict__ hbuf, u32* __restrict__ barrier)
{
  const int gid = blockIdx.x * blockDim.x + threadIdx.x;
  const int gsz = gridDim.x * blockDim.x;

  if (gid < 256) barrier[gid] = 0u;

  // xt[t][b][i] <- x[b][t][i]  (bf16, time-major)
  for (int v = gid; v < (S_ * B_ * I_ / 8); v += gsz) {
    int flat = v * 8;
    int t = flat / (B_ * I_);
    int r = flat - t * (B_ * I_);
    int b = r / I_;
    int i = r - b * I_;
    const float* s = x + (size_t)b * (S_ * I_) + (size_t)t * I_ + i;
    *(uint4*)(xt + flat) = cvt8(s);
  }

  // Wc[n][k]: n = (unit_block<<5) + u_local*4 + gate; k<1024 -> Wh, else Wx
  for (int v = gid; v < (4096 * 1536 / 8); v += gsz) {
    int n = v / 192;
    int k = (v - n * 192) * 8;
    int unit = ((n >> 5) << 3) + ((n >> 2) & 7);
    int g = n & 3;
    const float* Whp = (g == 0) ? Whf : (g == 1) ? Whi : (g == 2) ? Whg : Who;
    const float* Wxp = (g == 0) ? Wxf : (g == 1) ? Wxi : (g == 2) ? Wxg : Wxo;
    const float* s = (k < 1024) ? (Whp + (size_t)unit * 1024 + k)
                                : (Wxp + (size_t)unit * 512 + (k - 1024));
    *(uint4*)(Wc + (size_t)n * 1536 + k) = cvt8(s);
  }

  for (int n = gid; n < 4096; n += gsz) {
    int unit = ((n >> 5) << 3) + ((n >> 2) & 7);
    int g = n & 3;
    const float* bp = (g == 0) ? bfp : (g == 1) ? bip : (g == 2) ? bgp : bop;
    bc[n] = bp[unit];
  }

  for (int v = gid; v < (O_ * H_ / 8); v += gsz) {
    int flat = v * 8;
    *(uint4*)(WhyT + flat) = cvt8(Why + flat);
  }

  // zero h step-0 buffer (and step-1 area; harmless in both modes)
  for (int v = gid; v < (2 * B_ * H_ / 8); v += gsz) {
    uint4 z; z.x = 0; z.y = 0; z.z = 0; z.w = 0;
    *(uint4*)(hbuf + v * 8) = z;
  }
}

// ------------------------------------------------------ persistent LSTM ----
__global__ __launch_bounds__(256, 1) void lstm_seq(
    const u16* __restrict__ xt, const u16* __restrict__ Wc,
    const float* __restrict__ bc, u16* __restrict__ hbuf,
    const u16* __restrict__ WhyT, const float* __restrict__ WhyB,
    float* __restrict__ out, u32* __restrict__ barrier, int rotFlag)
{
  // 64 KB: A = 4 slots x 512 uint4 (32 rows x 128 k), B = 2 slots x 1024
  // uint4 (64 cols x 128 k). Swizzled: A idx = c16*32 + (r ^ (c16&7));
  // B idx = k16*64 + (col ^ (k16&7)). Writes 2-way (free), frag reads clean.
  __shared__ uint4 LDS[4096];
  uint4* AL = LDS;            // slots: AL + slot*512
  uint4* BL = LDS + 2048;     // slots: BL + slot*1024

  const int tid  = threadIdx.x;
  const int lane = tid & 63;
  const int w    = tid >> 6;
  const int ct   = w & 1;          // col-tile (32 cols)
  const int kh   = w >> 1;         // K-half of each 128-chunk
  const int rq   = blockIdx.x >> 6;   // batch quarter: rows rq*32..+32
  const int cg   = blockIdx.x & 63;   // col group: gate-cols cg*64..+64

  const bool rot = (rotFlag != 0);
  const int colN  = lane & 31;
  const int kgsel = lane >> 5;

  // staging thread->element map
  const int c16L = tid & 15;          // 16B-chunk within a 128-k window
  const int r0   = tid >> 4;          // rows r0 (p=0) / r0+16 (p=1) for A
  const int bcol0 = tid >> 4;         // B: col = p*16 + bcol0, k16 = c16L

  const u16* WcB = Wc + (size_t)(cg * 64) * 1536;
  const float bias = bc[cg * 64 + ct * 32 + colN];
  const int gate = colN & 3;
  const int unitL = ct * 8 + (colN >> 2);      // unit within group (0..15)

  float c[8];
#pragma unroll
  for (int i = 0; i < 8; ++i) c[i] = 0.f;

  uint4 xr[8], hr[16];
  BSet rb0, rb1;
  v16f accP0, accP1;

  auto ldB = [&](BSet& s, int cchunk) {
    size_t koff = (cchunk < 4) ? (size_t)(1024 + cchunk * 128) : (size_t)((cchunk - 4) * 128);
#pragma unroll
    for (int p = 0; p < 4; ++p) {
      int col = p * 16 + bcol0;
      s.b[p] = *(const uint4*)(WcB + (size_t)col * 1536 + koff + c16L * 8);
    }
  };
  auto wrB = [&](int slot, BSet& s) {
#pragma unroll
    for (int p = 0; p < 4; ++p) {
      int col = p * 16 + bcol0;
      BL[slot * 1024 + c16L * 64 + (col ^ (c16L & 7))] = s.b[p];
    }
  };
  auto wrA = [&](int chunk, uint4* regs, int regbase) {
    int slot = chunk & 3;
#pragma unroll
    for (int p = 0; p < 2; ++p) {
      int r = p * 16 + r0;
      AL[slot * 512 + c16L * 32 + (r ^ (c16L & 7))] = regs[regbase + p];
    }
  };
  auto mm = [&](int s) {
    int sa = (s & 3) * 512, sb = (s & 1) * 1024;
#pragma unroll
    for (int j = 0; j < 4; ++j) {
      int k8 = kh * 8 + j * 2 + kgsel;
      v8s aF = __builtin_bit_cast(v8s, AL[sa + k8 * 32 + (colN ^ (k8 & 7))]);
      v8s bF = __builtin_bit_cast(v8s, BL[sb + k8 * 64 + ((ct * 32 + colN) ^ (k8 & 7))]);
      if (j & 1) accP1 = __builtin_amdgcn_mfma_f32_32x32x16_bf16(aF, bF, accP1, 0, 0, 0);
      else       accP0 = __builtin_amdgcn_mfma_f32_32x32x16_bf16(aF, bF, accP0, 0, 0, 0);
    }
  };

#pragma unroll 1
  for (int t = 0; t < S_; ++t) {
    const size_t rdoff = rot ? (size_t)t * (B_ * H_) : (size_t)(t & 1) * (B_ * H_);
    const size_t wroff = rot ? (size_t)(t + 1) * (B_ * H_) : (size_t)((t & 1) ^ 1) * (B_ * H_);
    const u16* hb = hbuf + rdoff + (size_t)rq * 32 * H_;
    u16* hn = hbuf + wroff + (size_t)rq * 32 * H_;
    const u16* xb = xt + (size_t)t * (B_ * I_) + (size_t)rq * 32 * I_;

#pragma unroll
    for (int i = 0; i < 16; ++i) { accP0[i] = 0.f; accP1[i] = 0.f; }

    // ---- x A-regs (cached, coalesced 256B segments) ----
#pragma unroll
    for (int kb = 0; kb < 4; ++kb)
#pragma unroll
      for (int p = 0; p < 2; ++p)
        xr[kb * 2 + p] = *(const uint4*)(xb + (size_t)(p * 16 + r0) * I_ + (kb * 16 + c16L) * 8);

    ldB(rb0, 0); ldB(rb1, 1);
    wrA(0, xr, 0); wrA(1, xr, 2); wrA(2, xr, 4); wrA(3, xr, 6);
    wrB(0, rb0);
    __syncthreads();
    // x stages 0..3 (pre-barrier; B chunks 4,5 are Wc, no h dependence)
    ldB(rb0, 2); wrB(1, rb1); mm(0); __syncthreads();
    ldB(rb1, 3); wrB(0, rb0); mm(1); __syncthreads();
    ldB(rb0, 4); wrB(1, rb1); mm(2); __syncthreads();
    ldB(rb1, 5); wrB(0, rb0); mm(3); __syncthreads();

    // ---- rq-group barrier: h_{t-1} rows rq*32..+32 ready ----
    if (t > 0) {
      if (tid < 64) {
        u32 spins = 0;
        while (__hip_atomic_load(&barrier[rq * 64 + tid], __ATOMIC_RELAXED,
                                 __HIP_MEMORY_SCOPE_AGENT) < (u32)t) {
          __builtin_amdgcn_s_sleep(1);
          if (++spins > (1u << 22)) break;
        }
      }
      __syncthreads();
    }

    // ---- h A-regs: ONE coalesced burst (cached if rotating, else UC) ----
    if (rot) {
#pragma unroll
      for (int kb = 0; kb < 8; ++kb)
#pragma unroll
        for (int p = 0; p < 2; ++p)
          hr[kb * 2 + p] = *(const uint4*)(hb + (size_t)(p * 16 + r0) * H_ + (kb * 16 + c16L) * 8);
    } else {
#pragma unroll
      for (int kb = 0; kb < 8; ++kb)
#pragma unroll
        for (int p = 0; p < 2; ++p)
          hr[kb * 2 + p] = uc_ld16(hb + (size_t)(p * 16 + r0) * H_ + (kb * 16 + c16L) * 8);
    }
    wrA(4, hr, 0); wrA(5, hr, 2); wrA(6, hr, 4); wrA(7, hr, 6);
    wrB(1, rb1);
    __syncthreads();
    // h stages 4..11
    ldB(rb0, 6);                                 mm(4);  __syncthreads();
    ldB(rb1, 7); wrB(0, rb0); wrA(8, hr, 8);     mm(5);  __syncthreads();
    ldB(rb0, 8); wrB(1, rb1); wrA(9, hr, 10);    mm(6);  __syncthreads();
    ldB(rb1, 9); wrB(0, rb0); wrA(10, hr, 12);   mm(7);  __syncthreads();
    ldB(rb0,10); wrB(1, rb1); wrA(11, hr, 14);   mm(8);  __syncthreads();
    ldB(rb1,11); wrB(0, rb0);                    mm(9);  __syncthreads();
                 wrB(1, rb1);                    mm(10); __syncthreads();
                                                 mm(11); __syncthreads();

    // ---- cross-kh reduce (LDS in B area), gates, state update ----
    float aT[16];
#pragma unroll
    for (int i = 0; i < 16; ++i) aT[i] = accP0[i] + accP1[i];

    float* scr = (float*)BL;   // 8 KB scratch
    {
      int h2 = 1 - kh;
#pragma unroll
      for (int i = 0; i < 8; ++i)
        scr[ct * 1024 + h2 * 512 + i * 64 + lane] = aT[h2 * 8 + i];
    }
    __syncthreads();

    u16* hstage = (u16*)AL;   // 1 KB: [row 0..31][unitL 0..15]
    const bool lastT = (t == S_ - 1);
#pragma unroll
    for (int i = 0; i < 8; ++i) {
      int r = kh * 8 + i;
      float pre = aT[r] + scr[ct * 1024 + kh * 512 + i * 64 + lane] + bias;
      float e = __expf((gate == 2) ? (2.f * pre) : (-pre));
      float act = (gate == 2) ? (1.f - 2.f / (e + 1.f)) : (1.f / (1.f + e));
      int qb = lane & ~3;
      float F = __shfl(act, qb + 0, 64);
      float I = __shfl(act, qb + 1, 64);
      float G = __shfl(act, qb + 2, 64);
      float O = __shfl(act, qb + 3, 64);
      float cn = fmaf(F, c[i], I * G);
      c[i] = cn;
      float e2 = __expf(2.f * cn);
      float hv = O * (1.f - 2.f / (e2 + 1.f));
      if (gate == 0) {
        int rowL = (r & 3) + ((r >> 2) << 3) + (kgsel << 2);   // 0..31
        hstage[rowL * 16 + unitL] = f2bf(hv);
        if (lastT) {
          int grow = rq * 32 + rowL;
          int gunit = cg * 16 + unitL;
          out[65536 + grow * H_ + gunit] = hv;
          out[196608 + grow * H_ + gunit] = cn;
        }
      }
    }
    __syncthreads();

    // ---- coalesced h write: UC (write-through to fabric) ----
    if (tid < 64) {
      int row = tid >> 1, hf16 = tid & 1;
      uint4 v = ((const uint4*)hstage)[row * 2 + hf16];
      uc_st16(hn + (size_t)row * H_ + cg * 16 + hf16 * 8, v);
    }
    asm volatile("s_waitcnt vmcnt(0)" ::: "memory");
    __syncthreads();
    if (tid == 0)
      __hip_atomic_store(&barrier[rq * 64 + cg], (u32)(t + 1), __ATOMIC_RELAXED,
                         __HIP_MEMORY_SCOPE_AGENT);
  }

  // ---- full barrier, then out = h_final @ Why^T + b ----
  {
    u32 spins = 0;
    while (__hip_atomic_load(&barrier[tid], __ATOMIC_RELAXED,
                             __HIP_MEMORY_SCOPE_AGENT) < (u32)S_) {
      __builtin_amdgcn_s_sleep(2);
      if (++spins > (1u << 22)) break;
    }
  }
  __syncthreads();

  if (blockIdx.x < 32) {
    const int wg = blockIdx.x;
    const u16* hf = hbuf + (rot ? (size_t)S_ * (B_ * H_) : 0);
    const int l15 = lane & 15;
    const int l4 = lane >> 4;
    const int colO = (wg << 4) + l15;
    v4f o0, o1;
#pragma unroll
    for (int i = 0; i < 4; ++i) { o0[i] = 0.f; o1[i] = 0.f; }
#pragma unroll 4
    for (int kc = 0; kc < 32; ++kc) {
      v8s bfrag = *(const v8s*)(WhyT + (size_t)colO * H_ + kc * 32 + (l4 << 3));
      v8s a0, a1;
      if (rot) {
        a0 = *(const v8s*)(hf + (size_t)((w << 5) + l15) * H_ + kc * 32 + (l4 << 3));
        a1 = *(const v8s*)(hf + (size_t)((w << 5) + 16 + l15) * H_ + kc * 32 + (l4 << 3));
      } else {
        a0 = __builtin_bit_cast(v8s, uc_ld16(hf + (size_t)((w << 5) + l15) * H_ + kc * 32 + (l4 << 3)));
        a1 = __builtin_bit_cast(v8s, uc_ld16(hf + (size_t)((w << 5) + 16 + l15) * H_ + kc * 32 + (l4 << 3)));
      }
      o0 = __builtin_amdgcn_mfma_f32_16x16x32_bf16(a0, bfrag, o0, 0, 0, 0);
      o1 = __builtin_amdgcn_mfma_f32_16x16x32_bf16(a1, bfrag, o1, 0, 0, 0);
    }
    float bO = WhyB[colO];
#pragma unroll
    for (int r = 0; r < 4; ++r) {
      int row = (w << 5) + (l4 << 2) + r;
      out[row * O_ + colO] = o0[r] + bO;
      out[(row + 16) * O_ + colO] = o1[r] + bO;
    }
  }
}

// ------------------------------------------------------------- launch ----
extern "C" void kernel_launch(void* const* d_in, const int* in_sizes, int n_in,
                              void* d_out, int out_size, void* d_ws, size_t ws_size,
                              hipStream_t stream) {
  const float* x    = (const float*)d_in[0];
  const float* Wxf  = (const float*)d_in[1];
  const float* bf_  = (const float*)d_in[2];
  const float* Whf  = (const float*)d_in[3];
  const float* Wxi  = (const float*)d_in[4];
  const float* bi_  = (const float*)d_in[5];
  const float* Whi  = (const float*)d_in[6];
  const float* Wxg  = (const float*)d_in[7];
  const float* bg_  = (const float*)d_in[8];
  const float* Whg  = (const float*)d_in[9];
  const float* Wxo  = (const float*)d_in[10];
  const float* bo_  = (const float*)d_in[11];
  const float* Who  = (const float*)d_in[12];
  const float* Why  = (const float*)d_in[13];
  const float* Whyb = (const float*)d_in[14];

  char* ws = (char*)d_ws;
  u16*   xtp  = (u16*)(ws);                    // 33,554,432 B
  u16*   Wcp  = (u16*)(ws + 33554432);         // 12,582,912 B
  float* bcp  = (float*)(ws + 46137344);       //     16,384 B
  u16*   WhyT = (u16*)(ws + 46153728);         //  1,048,576 B
  u32*   barp = (u32*)(ws + 47202304);         //      1,024 B
  u16*   hbuf = (u16*)(ws + 47203328);         // rot: 257*256KB, else 512KB
  float* outp = (float*)d_out;

  const size_t need_rot = 47203328ull + 257ull * (size_t)(B_ * H_) * 2ull;
  int rot = (ws_size >= need_rot) ? 1 : 0;

  lstm_prep<<<dim3(1024), dim3(256), 0, stream>>>(
      x, Whf, Whi, Whg, Who, Wxf, Wxi, Wxg, Wxo,
      bf_, bi_, bg_, bo_, Why, xtp, Wcp, bcp, WhyT, hbuf, barp);

  lstm_seq<<<dim3(256), dim3(256), 0, stream>>>(
      xtp, Wcp, bcp, hbuf, WhyT, Whyb, outp, barp, rot);
}

// Round 7
// 4187.959 us; speedup vs baseline: 1.4811x; 1.4811x over previous
//
#include <hip/hip_runtime.h>

// LSTM: B=128, S=256, I=512, H=1024, O=512.
// R7: fragment-major everything; zero per-step LDS staging.
// 256 blocks x 256 thr: block = (rq = blockIdx>>6: rows rq*32..+31,
// cg = blockIdx&63: gate-cols cg*64..+63). Wave (ct = w&1: 32-col tile,
// kh = w>>1: K-half); cross-kh reduce via 8 KB LDS scratch (R6-proven).
// Global layouts (built by prep) make every hot-loop load coalesced:
//   xA[t][rq][w8][row]   : x in MFMA-A-frag order   (16B/lane, 1KB/wave)
//   WcF[w8][colG]        : weights in B-frag order  (L2-resident per XCD)
//   hA[t][rq][w8][row]   : h in A-frag order; produced coalesced (UC stores),
//                          consumed CACHED from per-step rotating buffers --
//                          lines are never cached before their producer's UC
//                          store (one-time acquire fence at kernel start
//                          drops stale memset/prep lines), so cold-miss reads
//                          are correct and per-XCD L2 dedups the broadcast.
//                          UC-read fallback if ws too small for 257 buffers.
// Sync: distributed-slot barrier per rq-group, relaxed agent atomics, no
// per-step fences (R3: agent fences = whole-L2 wbl2/inv, measured disaster).
// NO register arrays with runtime indices (R6 regression: scratch spill).

#define B_ 128
#define S_ 256
#define I_ 512
#define H_ 1024
#define O_ 512

typedef unsigned short u16;
typedef unsigned int u32;
typedef unsigned long long u64;

typedef short v8s __attribute__((ext_vector_type(8)));
typedef float v16f __attribute__((ext_vector_type(16)));
typedef float v4f __attribute__((ext_vector_type(4)));

__device__ __forceinline__ u16 f2bf(float f) {
  u32 u = __float_as_uint(f);
  u32 r = (u + 0x7fffu + ((u >> 16) & 1u)) >> 16;   // RNE
  return (u16)r;
}
__device__ __forceinline__ u32 pack2(float a, float b) {
  return (u32)f2bf(a) | ((u32)f2bf(b) << 16);
}
__device__ __forceinline__ uint4 cvt8(const float* __restrict__ s) {
  float4 f0 = ((const float4*)s)[0];
  float4 f1 = ((const float4*)s)[1];
  uint4 o;
  o.x = pack2(f0.x, f0.y); o.y = pack2(f0.z, f0.w);
  o.z = pack2(f1.x, f1.y); o.w = pack2(f1.z, f1.w);
  return o;
}

// 16B via relaxed agent-scope atomic u64 pairs (coherent at fabric/MALL,
// bypasses non-coherent L1/L2, no cache-maintenance side effects).
__device__ __forceinline__ uint4 uc_ld16(const u16* p) {
  u64 lo = __hip_atomic_load((const u64*)p, __ATOMIC_RELAXED, __HIP_MEMORY_SCOPE_AGENT);
  u64 hi = __hip_atomic_load((const u64*)p + 1, __ATOMIC_RELAXED, __HIP_MEMORY_SCOPE_AGENT);
  uint4 v; v.x = (u32)lo; v.y = (u32)(lo >> 32); v.z = (u32)hi; v.w = (u32)(hi >> 32);
  return v;
}
__device__ __forceinline__ void uc_st16(u16* p, uint4 v) {
  u64 lo = (u64)v.x | ((u64)v.y << 32);
  u64 hi = (u64)v.z | ((u64)v.w << 32);
  __hip_atomic_store((u64*)p, lo, __ATOMIC_RELAXED, __HIP_MEMORY_SCOPE_AGENT);
  __hip_atomic_store((u64*)p + 1, hi, __ATOMIC_RELAXED, __HIP_MEMORY_SCOPE_AGENT);
}

// ---------------------------------------------------------------- prep ----
__global__ void lstm_prep(
    const float* __restrict__ x,
    const float* __restrict__ Whf, const float* __restrict__ Whi,
    const float* __restrict__ Whg, const float* __restrict__ Who,
    const float* __restrict__ Wxf, const float* __restrict__ Wxi,
    const float* __restrict__ Wxg, const float* __restrict__ Wxo,
    const float* __restrict__ bfp, const float* __restrict__ bip,
    const float* __restrict__ bgp, const float* __restrict__ bop,
    const float* __restrict__ Why,
    u16* __restrict__ xt, u16* __restrict__ Wc, float* __restrict__ bc,
    u16* __restrict__ WhyT, u16* __restrict__ hbuf, u32* __restrict__ barrier)
{
  const int gid = blockIdx.x * blockDim.x + threadIdx.x;
  const int gsz = gridDim.x * blockDim.x;

  if (gid < 256) barrier[gid] = 0u;

  // xA[t][rq][w8 0..63][row 0..31] (16B units) <- x[b=rq*32+row][t][w8*8..+8]
  // source-linear iteration: coalesced fp32 reads, scattered 16B writes.
  for (int v = gid; v < (S_ * B_ * I_ / 8); v += gsz) {
    int flat = v * 8;
    int b = flat / (S_ * I_);
    int rem = flat - b * (S_ * I_);
    int t = rem / I_;
    int i = rem - t * I_;
    size_t dst = ((size_t)(t * 4 + (b >> 5)) * 64 + (i >> 3)) * 32 + (b & 31);
    ((uint4*)xt)[dst] = cvt8(x + flat);
  }

  // WcF[w8 0..191][colG 0..4095]: w8<64 -> Wx k=w8*8 ; w8>=64 -> Wh k=(w8-64)*8
  // colG -> unit/gate: unit = (cg)*16 + (ct)*8 + (colN>>2), gate = colG&3
  for (int o = gid; o < 192 * 4096; o += gsz) {
    int w8 = o >> 12;
    int colG = o & 4095;
    int unit = ((colG >> 6) << 4) + (((colG >> 5) & 1) << 3) + ((colG >> 2) & 7);
    int g = colG & 3;
    const float* Whp = (g == 0) ? Whf : (g == 1) ? Whi : (g == 2) ? Whg : Who;
    const float* Wxp = (g == 0) ? Wxf : (g == 1) ? Wxi : (g == 2) ? Wxg : Wxo;
    const float* s = (w8 < 64) ? (Wxp + (size_t)unit * 512 + w8 * 8)
                               : (Whp + (size_t)unit * 1024 + (w8 - 64) * 8);
    ((uint4*)Wc)[o] = cvt8(s);
  }

  // bias (colG-indexed)
  for (int n = gid; n < 4096; n += gsz) {
    int unit = ((n >> 6) << 4) + (((n >> 5) & 1) << 3) + ((n >> 2) & 7);
    int g = n & 3;
    const float* bp = (g == 0) ? bfp : (g == 1) ? bip : (g == 2) ? bgp : bop;
    bc[n] = bp[unit];
  }

  // Why -> bf16 (row-major [o][k])
  for (int v = gid; v < (O_ * H_ / 8); v += gsz) {
    int flat = v * 8;
    *(uint4*)(WhyT + flat) = cvt8(Why + flat);
  }

  // zero hA[0] and hA[1]
  for (int v = gid; v < 2 * 16384; v += gsz) {
    uint4 z; z.x = 0; z.y = 0; z.z = 0; z.w = 0;
    ((uint4*)hbuf)[v] = z;
  }
}

// ------------------------------------------------------ persistent LSTM ----
__global__ __launch_bounds__(256, 1) void lstm_seq(
    const u16* __restrict__ xt, const u16* __restrict__ Wc,
    const float* __restrict__ bc, u16* __restrict__ hbuf,
    const u16* __restrict__ WhyT, const float* __restrict__ WhyB,
    float* __restrict__ out, u32* __restrict__ barrier, int rotFlag)
{
  __shared__ float scr[2048];   // cross-kh partial-sum exchange (8 KB)
  __shared__ u16 hstage[512];   // h gather tile: [row 0..31][unitL 0..15]

  const int tid  = threadIdx.x;
  const int lane = tid & 63;
  const int w    = tid >> 6;
  const int ct   = w & 1;             // col tile (32 cols)
  const int kh   = w >> 1;            // K half
  const int rq   = blockIdx.x >> 6;   // rows rq*32..+31
  const int cg   = blockIdx.x & 63;   // gate-cols cg*64..+63
  const bool rot = (rotFlag != 0);

  const int colN  = lane & 31;
  const int kgsel = lane >> 5;
  const int colG  = cg * 64 + ct * 32 + colN;
  const int gate  = colN & 3;                 // 0=f 1=i 2=g 3=o
  const int unitL = ct * 8 + (colN >> 2);
  const float bias = bc[colG];

  const uint4* xA4  = (const uint4*)xt;
  const uint4* WcF4 = (const uint4*)Wc;
  uint4*       HA4  = (uint4*)hbuf;

  const int xaOff = rq * 2048 + kh * 1024 + lane;                 // + t*8192 + kb*64
  const int xbOff = kh * 131072 + kgsel * 4096 + colG;            // + kb*8192
  const int haOff = rq * 4096 + kh * 2048 + lane;                 // + tb + kb*64
  const int hbOff = 262144 + kh * 262144 + kgsel * 4096 + colG;   // + kb*8192

  float c[8];
#pragma unroll
  for (int i = 0; i < 8; ++i) c[i] = 0.f;

  // One-time acquire (L1/L2 invalidate): drop stale memset-poison / prep
  // lines so cached reads of rotating h buffers are cold-miss-correct.
  __builtin_amdgcn_fence(__ATOMIC_ACQUIRE, "agent");
  __syncthreads();

  v16f acc0, acc1;

#pragma unroll 1
  for (int t = 0; t < S_; ++t) {
    const size_t tb = rot ? (size_t)t * 16384 : (size_t)(t & 1) * 16384;
    const size_t tn = rot ? (size_t)(t + 1) * 16384 : (size_t)((t & 1) ^ 1) * 16384;

#pragma unroll
    for (int i = 0; i < 16; ++i) { acc0[i] = 0.f; acc1[i] = 0.f; }

    // ---- x-phase: direct frag loads (cached), no h dependence ----
    {
      const uint4* ax = xA4 + (size_t)t * 8192 + xaOff;
      const uint4* bx = WcF4 + xbOff;
#pragma unroll
      for (int kb = 0; kb < 16; ++kb) {
        v8s aF = __builtin_bit_cast(v8s, ax[kb * 64]);
        v8s bF = __builtin_bit_cast(v8s, bx[(size_t)kb * 8192]);
        if (kb & 1) acc1 = __builtin_amdgcn_mfma_f32_32x32x16_bf16(aF, bF, acc1, 0, 0, 0);
        else        acc0 = __builtin_amdgcn_mfma_f32_32x32x16_bf16(aF, bF, acc0, 0, 0, 0);
      }
    }

    // ---- rq-group barrier: h_{t-1} rows ready ----
    if (t > 0) {
      if (tid < 64) {
        u32 spins = 0;
        while (__hip_atomic_load(&barrier[rq * 64 + tid], __ATOMIC_RELAXED,
                                 __HIP_MEMORY_SCOPE_AGENT) < (u32)t) {
          __builtin_amdgcn_s_sleep(1);
          if (++spins > (1u << 22)) break;   // safety valve
        }
      }
      __syncthreads();
    }

    // ---- h-phase: direct frag loads; A cached (rot) or UC (fallback) ----
    {
      const uint4* ah = HA4 + tb + haOff;
      const uint4* bh = WcF4 + hbOff;
      if (rot) {
#pragma unroll
        for (int kb = 0; kb < 32; ++kb) {
          v8s aF = __builtin_bit_cast(v8s, ah[kb * 64]);
          v8s bF = __builtin_bit_cast(v8s, bh[(size_t)kb * 8192]);
          if (kb & 1) acc1 = __builtin_amdgcn_mfma_f32_32x32x16_bf16(aF, bF, acc1, 0, 0, 0);
          else        acc0 = __builtin_amdgcn_mfma_f32_32x32x16_bf16(aF, bF, acc0, 0, 0, 0);
        }
      } else {
#pragma unroll
        for (int kb = 0; kb < 32; ++kb) {
          v8s aF = __builtin_bit_cast(v8s, uc_ld16((const u16*)(ah + kb * 64)));
          v8s bF = __builtin_bit_cast(v8s, bh[(size_t)kb * 8192]);
          if (kb & 1) acc1 = __builtin_amdgcn_mfma_f32_32x32x16_bf16(aF, bF, acc1, 0, 0, 0);
          else        acc0 = __builtin_amdgcn_mfma_f32_32x32x16_bf16(aF, bF, acc0, 0, 0, 0);
        }
      }
    }

    // ---- cross-kh reduce, gates, state update ----
    float aT[16];
#pragma unroll
    for (int i = 0; i < 16; ++i) aT[i] = acc0[i] + acc1[i];
    {
      int h2 = 1 - kh;
#pragma unroll
      for (int i = 0; i < 8; ++i)
        scr[ct * 1024 + h2 * 512 + i * 64 + lane] = aT[h2 * 8 + i];
    }
    __syncthreads();

    const bool lastT = (t == S_ - 1);
#pragma unroll
    for (int i = 0; i < 8; ++i) {
      int r = kh * 8 + i;
      float pre = aT[r] + scr[ct * 1024 + kh * 512 + i * 64 + lane] + bias;
      // gate 2 -> tanh (overflow-safe), others -> sigmoid
      float e = __expf((gate == 2) ? (2.f * pre) : (-pre));
      float act = (gate == 2) ? (1.f - 2.f / (e + 1.f)) : (1.f / (1.f + e));
      int qb = lane & ~3;   // quad holds f,i,g,o of one (row,unit)
      float F = __shfl(act, qb + 0, 64);
      float I = __shfl(act, qb + 1, 64);
      float G = __shfl(act, qb + 2, 64);
      float O = __shfl(act, qb + 3, 64);
      float cn = fmaf(F, c[i], I * G);
      c[i] = cn;
      float e2 = __expf(2.f * cn);
      float hv = O * (1.f - 2.f / (e2 + 1.f));
      if (gate == 0) {
        int rowL = (r & 3) + ((r >> 2) << 3) + (kgsel << 2);   // 0..31
        hstage[rowL * 16 + unitL] = f2bf(hv);
        if (lastT) {
          int grow = rq * 32 + rowL;
          int gunit = cg * 16 + unitL;
          out[65536 + grow * H_ + gunit] = hv;    // h output (fp32)
          out[196608 + grow * H_ + gunit] = cn;   // c output (fp32)
        }
      }
    }
    __syncthreads();

    // ---- coalesced h publish: 16B UC stores in hA frag layout ----
    if (tid < 64) {
      int row = tid >> 1, u16sel = tid & 1;
      uint4 v = ((const uint4*)hstage)[tid];
      uc_st16((u16*)(HA4 + tn + rq * 4096 + (size_t)(2 * cg + u16sel) * 32 + row), v);
    }
    asm volatile("s_waitcnt vmcnt(0)" ::: "memory");
    __syncthreads();
    if (tid == 0)
      __hip_atomic_store(&barrier[rq * 64 + cg], (u32)(t + 1), __ATOMIC_RELAXED,
                         __HIP_MEMORY_SCOPE_AGENT);
  }

  // ---- full barrier, then out = h_final @ Why^T + b ----
  {
    u32 spins = 0;
    while (__hip_atomic_load(&barrier[tid], __ATOMIC_RELAXED,
                             __HIP_MEMORY_SCOPE_AGENT) < (u32)S_) {
      __builtin_amdgcn_s_sleep(2);
      if (++spins > (1u << 22)) break;
    }
  }
  __syncthreads();

  if (blockIdx.x < 32) {
    const int wg = blockIdx.x;
    const uint4* HF = HA4 + (rot ? (size_t)S_ * 16384 : 0);
    const int l15 = lane & 15;
    const int l4 = lane >> 4;
    const int colO = (wg << 4) + l15;
    v4f o0, o1;
#pragma unroll
    for (int i = 0; i < 4; ++i) { o0[i] = 0.f; o1[i] = 0.f; }
#pragma unroll 4
    for (int kc = 0; kc < 32; ++kc) {
      v8s bfrag = *(const v8s*)(WhyT + (size_t)colO * H_ + kc * 32 + (l4 << 3));
      // hA frag layout: idx = rq*4096 + w8*32 + rowL ; w8 = kc*4 + l4
      size_t i0 = (size_t)w * 4096 + kc * 128 + l4 * 32 + l15;
      v8s a0, a1;
      if (rot) {
        a0 = __builtin_bit_cast(v8s, HF[i0]);
        a1 = __builtin_bit_cast(v8s, HF[i0 + 16]);
      } else {
        a0 = __builtin_bit_cast(v8s, uc_ld16((const u16*)(HF + i0)));
        a1 = __builtin_bit_cast(v8s, uc_ld16((const u16*)(HF + i0 + 16)));
      }
      o0 = __builtin_amdgcn_mfma_f32_16x16x32_bf16(a0, bfrag, o0, 0, 0, 0);
      o1 = __builtin_amdgcn_mfma_f32_16x16x32_bf16(a1, bfrag, o1, 0, 0, 0);
    }
    float bO = WhyB[colO];
#pragma unroll
    for (int r2 = 0; r2 < 4; ++r2) {
      int row = (w << 5) + (l4 << 2) + r2;
      out[row * O_ + colO] = o0[r2] + bO;
      out[(row + 16) * O_ + colO] = o1[r2] + bO;
    }
  }
}

// ------------------------------------------------------------- launch ----
extern "C" void kernel_launch(void* const* d_in, const int* in_sizes, int n_in,
                              void* d_out, int out_size, void* d_ws, size_t ws_size,
                              hipStream_t stream) {
  const float* x    = (const float*)d_in[0];
  const float* Wxf  = (const float*)d_in[1];
  const float* bf_  = (const float*)d_in[2];
  const float* Whf  = (const float*)d_in[3];
  const float* Wxi  = (const float*)d_in[4];
  const float* bi_  = (const float*)d_in[5];
  const float* Whi  = (const float*)d_in[6];
  const float* Wxg  = (const float*)d_in[7];
  const float* bg_  = (const float*)d_in[8];
  const float* Whg  = (const float*)d_in[9];
  const float* Wxo  = (const float*)d_in[10];
  const float* bo_  = (const float*)d_in[11];
  const float* Who  = (const float*)d_in[12];
  const float* Why  = (const float*)d_in[13];
  const float* Whyb = (const float*)d_in[14];

  char* ws = (char*)d_ws;
  u16*   xtp  = (u16*)(ws);                    // xA: 33,554,432 B
  u16*   Wcp  = (u16*)(ws + 33554432);         // WcF: 12,582,912 B
  float* bcp  = (float*)(ws + 46137344);       //     16,384 B
  u16*   WhyT = (u16*)(ws + 46153728);         //  1,048,576 B
  u32*   barp = (u32*)(ws + 47202304);         //      1,024 B
  u16*   hbuf = (u16*)(ws + 47203328);         // hA: rot 257*256KB else 512KB
  float* outp = (float*)d_out;

  const size_t need_rot = 47203328ull + 257ull * 262144ull;  // ~114.6 MB
  int rot = (ws_size >= need_rot) ? 1 : 0;

  lstm_prep<<<dim3(1024), dim3(256), 0, stream>>>(
      x, Whf, Whi, Whg, Who, Wxf, Wxi, Wxg, Wxo,
      bf_, bi_, bg_, bo_, Why, xtp, Wcp, bcp, WhyT, hbuf, barp);

  lstm_seq<<<dim3(256), dim3(256), 0, stream>>>(
      xtp, Wcp, bcp, hbuf, WhyT, Whyb, outp, barp, rot);
}

// Round 8
// 2092.752 us; speedup vs baseline: 2.9640x; 2.0012x over previous
//
#include <hip/hip_runtime.h>

// LSTM: B=128, S=256, I=512, H=1024, O=512.
// R8 = R7 (fragment-major layouts, zero per-step LDS staging) +
//  (1) ALL 48 B-frags (weights) preloaded into registers ONCE (192 regs/lane,
//      AV class -> AGPR-eligible at occupancy 1; 512-reg unified file).
//      Weights never read from memory in the step loop.
//  (2) Deep A prefetch: 16 x-A / 32 h-A loads issued in one unrolled burst
//      (compile-time indices only -- R6 lesson: runtime-indexed register
//      arrays demote to scratch).
//  (3) Publish (hstage read + UC stores + vmcnt drain + flag) is wave0-only;
//      no trailing syncthreads, so waves 1..3 start step t+1's x-loads under
//      the store-ack round trip. Reconvergence at the wait's syncthreads.
// 256 blocks x 256 thr: block = (rq = blockIdx>>6: rows rq*32..+31,
// cg = blockIdx&63: gate-cols cg*64..+63). Wave (ct = w&1, kh = w>>1).
// h: produced via UC stores (relaxed agent atomics, write-through to fabric),
// consumed CACHED from per-step rotating buffers (cold-miss-correct; one-time
// acquire fence at start drops stale lines). UC-read fallback if ws small.
// Sync: distributed-slot barrier per rq group, relaxed atomics, no per-step
// fences (R3: agent fences = whole-L2 wbl2/inv, measured disaster).

#define B_ 128
#define S_ 256
#define I_ 512
#define H_ 1024
#define O_ 512

typedef unsigned short u16;
typedef unsigned int u32;
typedef unsigned long long u64;

typedef short v8s __attribute__((ext_vector_type(8)));
typedef float v16f __attribute__((ext_vector_type(16)));
typedef float v4f __attribute__((ext_vector_type(4)));

__device__ __forceinline__ u16 f2bf(float f) {
  u32 u = __float_as_uint(f);
  u32 r = (u + 0x7fffu + ((u >> 16) & 1u)) >> 16;   // RNE
  return (u16)r;
}
__device__ __forceinline__ u32 pack2(float a, float b) {
  return (u32)f2bf(a) | ((u32)f2bf(b) << 16);
}
__device__ __forceinline__ uint4 cvt8(const float* __restrict__ s) {
  float4 f0 = ((const float4*)s)[0];
  float4 f1 = ((const float4*)s)[1];
  uint4 o;
  o.x = pack2(f0.x, f0.y); o.y = pack2(f0.z, f0.w);
  o.z = pack2(f1.x, f1.y); o.w = pack2(f1.z, f1.w);
  return o;
}

__device__ __forceinline__ uint4 uc_ld16(const u16* p) {
  u64 lo = __hip_atomic_load((const u64*)p, __ATOMIC_RELAXED, __HIP_MEMORY_SCOPE_AGENT);
  u64 hi = __hip_atomic_load((const u64*)p + 1, __ATOMIC_RELAXED, __HIP_MEMORY_SCOPE_AGENT);
  uint4 v; v.x = (u32)lo; v.y = (u32)(lo >> 32); v.z = (u32)hi; v.w = (u32)(hi >> 32);
  return v;
}
__device__ __forceinline__ void uc_st16(u16* p, uint4 v) {
  u64 lo = (u64)v.x | ((u64)v.y << 32);
  u64 hi = (u64)v.z | ((u64)v.w << 32);
  __hip_atomic_store((u64*)p, lo, __ATOMIC_RELAXED, __HIP_MEMORY_SCOPE_AGENT);
  __hip_atomic_store((u64*)p + 1, hi, __ATOMIC_RELAXED, __HIP_MEMORY_SCOPE_AGENT);
}

// ---------------------------------------------------------------- prep ----
__global__ void lstm_prep(
    const float* __restrict__ x,
    const float* __restrict__ Whf, const float* __restrict__ Whi,
    const float* __restrict__ Whg, const float* __restrict__ Who,
    const float* __restrict__ Wxf, const float* __restrict__ Wxi,
    const float* __restrict__ Wxg, const float* __restrict__ Wxo,
    const float* __restrict__ bfp, const float* __restrict__ bip,
    const float* __restrict__ bgp, const float* __restrict__ bop,
    const float* __restrict__ Why,
    u16* __restrict__ xt, u16* __restrict__ Wc, float* __restrict__ bc,
    u16* __restrict__ WhyT, u16* __restrict__ hbuf, u32* __restrict__ barrier)
{
  const int gid = blockIdx.x * blockDim.x + threadIdx.x;
  const int gsz = gridDim.x * blockDim.x;

  if (gid < 256) barrier[gid] = 0u;

  // xA[t][rq][w8 0..63][row 0..31] (16B units) <- x[b=rq*32+row][t][w8*8..+8]
  for (int v = gid; v < (S_ * B_ * I_ / 8); v += gsz) {
    int flat = v * 8;
    int b = flat / (S_ * I_);
    int rem = flat - b * (S_ * I_);
    int t = rem / I_;
    int i = rem - t * I_;
    size_t dst = ((size_t)(t * 4 + (b >> 5)) * 64 + (i >> 3)) * 32 + (b & 31);
    ((uint4*)xt)[dst] = cvt8(x + flat);
  }

  // WcF[w8 0..191][colG 0..4095]: w8<64 -> Wx k=w8*8 ; w8>=64 -> Wh k=(w8-64)*8
  for (int o = gid; o < 192 * 4096; o += gsz) {
    int w8 = o >> 12;
    int colG = o & 4095;
    int unit = ((colG >> 6) << 4) + (((colG >> 5) & 1) << 3) + ((colG >> 2) & 7);
    int g = colG & 3;
    const float* Whp = (g == 0) ? Whf : (g == 1) ? Whi : (g == 2) ? Whg : Who;
    const float* Wxp = (g == 0) ? Wxf : (g == 1) ? Wxi : (g == 2) ? Wxg : Wxo;
    const float* s = (w8 < 64) ? (Wxp + (size_t)unit * 512 + w8 * 8)
                               : (Whp + (size_t)unit * 1024 + (w8 - 64) * 8);
    ((uint4*)Wc)[o] = cvt8(s);
  }

  // bias (colG-indexed)
  for (int n = gid; n < 4096; n += gsz) {
    int unit = ((n >> 6) << 4) + (((n >> 5) & 1) << 3) + ((n >> 2) & 7);
    int g = n & 3;
    const float* bp = (g == 0) ? bfp : (g == 1) ? bip : (g == 2) ? bgp : bop;
    bc[n] = bp[unit];
  }

  // Why -> bf16 (row-major [o][k])
  for (int v = gid; v < (O_ * H_ / 8); v += gsz) {
    int flat = v * 8;
    *(uint4*)(WhyT + flat) = cvt8(Why + flat);
  }

  // zero hA[0] and hA[1]
  for (int v = gid; v < 2 * 16384; v += gsz) {
    uint4 z; z.x = 0; z.y = 0; z.z = 0; z.w = 0;
    ((uint4*)hbuf)[v] = z;
  }
}

// ------------------------------------------------------ persistent LSTM ----
__global__ __launch_bounds__(256, 1) void lstm_seq(
    const u16* __restrict__ xt, const u16* __restrict__ Wc,
    const float* __restrict__ bc, u16* __restrict__ hbuf,
    const u16* __restrict__ WhyT, const float* __restrict__ WhyB,
    float* __restrict__ out, u32* __restrict__ barrier, int rotFlag)
{
  __shared__ float scr[2048];   // cross-kh partial-sum exchange (8 KB)
  __shared__ u16 hstage[512];   // h gather tile: [row 0..31][unitL 0..15]

  const int tid  = threadIdx.x;
  const int lane = tid & 63;
  const int w    = tid >> 6;
  const int ct   = w & 1;             // col tile (32 cols)
  const int kh   = w >> 1;            // K half
  const int rq   = blockIdx.x >> 6;   // rows rq*32..+31
  const int cg   = blockIdx.x & 63;   // gate-cols cg*64..+63
  const bool rot = (rotFlag != 0);

  const int colN  = lane & 31;
  const int kgsel = lane >> 5;
  const int colG  = cg * 64 + ct * 32 + colN;
  const int gate  = colN & 3;                 // 0=f 1=i 2=g 3=o
  const int unitL = ct * 8 + (colN >> 2);
  const float bias = bc[colG];

  const uint4* xA4  = (const uint4*)xt;
  const uint4* WcF4 = (const uint4*)Wc;
  uint4*       HA4  = (uint4*)hbuf;

  const int xaOff = rq * 2048 + kh * 1024 + lane;                 // + t*8192 + kb*64
  const int xbOff = kh * 131072 + kgsel * 4096 + colG;            // + kb*8192
  const int haOff = rq * 4096 + kh * 2048 + lane;                 // + tb + kb*64
  const int hbOff = 262144 + kh * 262144 + kgsel * 4096 + colG;   // + kb*8192

  float c[8];
#pragma unroll
  for (int i = 0; i < 8; ++i) c[i] = 0.f;

  // One-time acquire: drop stale memset-poison / pre-prep lines so cached
  // reads of rotating h buffers (and the B preload) are correct.
  __builtin_amdgcn_fence(__ATOMIC_ACQUIRE, "agent");
  __syncthreads();

  // ---- park ALL weight B-frags in registers (192 regs/lane, AV->AGPR) ----
  v8s Bx[16], Bh[32];
  {
    const uint4* bx = WcF4 + xbOff;
#pragma unroll
    for (int kb = 0; kb < 16; ++kb)
      Bx[kb] = __builtin_bit_cast(v8s, bx[(size_t)kb * 8192]);
    const uint4* bh = WcF4 + hbOff;
#pragma unroll
    for (int kb = 0; kb < 32; ++kb)
      Bh[kb] = __builtin_bit_cast(v8s, bh[(size_t)kb * 8192]);
  }

  v16f acc0, acc1;

#pragma unroll 1
  for (int t = 0; t < S_; ++t) {
    const size_t tb = rot ? (size_t)t * 16384 : (size_t)(t & 1) * 16384;
    const size_t tn = rot ? (size_t)(t + 1) * 16384 : (size_t)((t & 1) ^ 1) * 16384;

#pragma unroll
    for (int i = 0; i < 16; ++i) { acc0[i] = 0.f; acc1[i] = 0.f; }

    // ---- x-phase: burst-load 16 A-frags, then MFMA against parked Bx ----
    {
      const uint4* ax = xA4 + (size_t)t * 8192 + xaOff;
      v8s xr[16];
#pragma unroll
      for (int kb = 0; kb < 16; ++kb)
        xr[kb] = __builtin_bit_cast(v8s, ax[kb * 64]);
#pragma unroll
      for (int kb = 0; kb < 16; ++kb) {
        if (kb & 1) acc1 = __builtin_amdgcn_mfma_f32_32x32x16_bf16(xr[kb], Bx[kb], acc1, 0, 0, 0);
        else        acc0 = __builtin_amdgcn_mfma_f32_32x32x16_bf16(xr[kb], Bx[kb], acc0, 0, 0, 0);
      }
    }

    // ---- rq-group barrier: h_{t-1} rows ready ----
    if (t > 0) {
      if (tid < 64) {
        u32 spins = 0;
        while (__hip_atomic_load(&barrier[rq * 64 + tid], __ATOMIC_RELAXED,
                                 __HIP_MEMORY_SCOPE_AGENT) < (u32)t) {
          __builtin_amdgcn_s_sleep(1);
          if (++spins > (1u << 22)) break;   // safety valve
        }
      }
      __syncthreads();
    }

    // ---- h-phase: burst-load 32 A-frags, MFMA against parked Bh ----
    {
      const uint4* ah = HA4 + tb + haOff;
      v8s hr[32];
      if (rot) {
#pragma unroll
        for (int kb = 0; kb < 32; ++kb)
          hr[kb] = __builtin_bit_cast(v8s, ah[kb * 64]);
      } else {
#pragma unroll
        for (int kb = 0; kb < 32; ++kb)
          hr[kb] = __builtin_bit_cast(v8s, uc_ld16((const u16*)(ah + kb * 64)));
      }
#pragma unroll
      for (int kb = 0; kb < 32; ++kb) {
        if (kb & 1) acc1 = __builtin_amdgcn_mfma_f32_32x32x16_bf16(hr[kb], Bh[kb], acc1, 0, 0, 0);
        else        acc0 = __builtin_amdgcn_mfma_f32_32x32x16_bf16(hr[kb], Bh[kb], acc0, 0, 0, 0);
      }
    }

    // ---- cross-kh reduce, gates, state update ----
    float aT[16];
#pragma unroll
    for (int i = 0; i < 16; ++i) aT[i] = acc0[i] + acc1[i];
    {
      int h2 = 1 - kh;
#pragma unroll
      for (int i = 0; i < 8; ++i)
        scr[ct * 1024 + h2 * 512 + i * 64 + lane] = aT[h2 * 8 + i];
    }
    __syncthreads();

    const bool lastT = (t == S_ - 1);
#pragma unroll
    for (int i = 0; i < 8; ++i) {
      int r = kh * 8 + i;
      float pre = aT[r] + scr[ct * 1024 + kh * 512 + i * 64 + lane] + bias;
      // gate 2 -> tanh (overflow-safe), others -> sigmoid
      float e = __expf((gate == 2) ? (2.f * pre) : (-pre));
      float act = (gate == 2) ? (1.f - 2.f / (e + 1.f)) : (1.f / (1.f + e));
      int qb = lane & ~3;   // quad holds f,i,g,o of one (row,unit)
      float F = __shfl(act, qb + 0, 64);
      float I = __shfl(act, qb + 1, 64);
      float G = __shfl(act, qb + 2, 64);
      float O = __shfl(act, qb + 3, 64);
      float cn = fmaf(F, c[i], I * G);
      c[i] = cn;
      float e2 = __expf(2.f * cn);
      float hv = O * (1.f - 2.f / (e2 + 1.f));
      if (gate == 0) {
        int rowL = (r & 3) + ((r >> 2) << 3) + (kgsel << 2);   // 0..31
        hstage[rowL * 16 + unitL] = f2bf(hv);
        if (lastT) {
          int grow = rq * 32 + rowL;
          int gunit = cg * 16 + unitL;
          out[65536 + grow * H_ + gunit] = hv;    // h output (fp32)
          out[196608 + grow * H_ + gunit] = cn;   // c output (fp32)
        }
      }
    }
    __syncthreads();

    // ---- publish: wave0 only (other waves run ahead to x of t+1; they
    // re-converge at the next wait's syncthreads, which also protects the
    // scr/hstage reuse ordering). ----
    if (tid < 64) {
      int row = tid >> 1, u16sel = tid & 1;
      uint4 v = ((const uint4*)hstage)[tid];
      uc_st16((u16*)(HA4 + tn + rq * 4096 + (size_t)(2 * cg + u16sel) * 32 + row), v);
      asm volatile("s_waitcnt vmcnt(0)" ::: "memory");
      if (tid == 0)
        __hip_atomic_store(&barrier[rq * 64 + cg], (u32)(t + 1), __ATOMIC_RELAXED,
                           __HIP_MEMORY_SCOPE_AGENT);
    }
  }

  // ---- full barrier, then out = h_final @ Why^T + b ----
  {
    u32 spins = 0;
    while (__hip_atomic_load(&barrier[tid], __ATOMIC_RELAXED,
                             __HIP_MEMORY_SCOPE_AGENT) < (u32)S_) {
      __builtin_amdgcn_s_sleep(2);
      if (++spins > (1u << 22)) break;
    }
  }
  __syncthreads();

  if (blockIdx.x < 32) {
    const int wg = blockIdx.x;
    const uint4* HF = HA4 + (rot ? (size_t)S_ * 16384 : 0);
    const int l15 = lane & 15;
    const int l4 = lane >> 4;
    const int colO = (wg << 4) + l15;
    v4f o0, o1;
#pragma unroll
    for (int i = 0; i < 4; ++i) { o0[i] = 0.f; o1[i] = 0.f; }
#pragma unroll 4
    for (int kc = 0; kc < 32; ++kc) {
      v8s bfrag = *(const v8s*)(WhyT + (size_t)colO * H_ + kc * 32 + (l4 << 3));
      size_t i0 = (size_t)w * 4096 + kc * 128 + l4 * 32 + l15;
      v8s a0, a1;
      if (rot) {
        a0 = __builtin_bit_cast(v8s, HF[i0]);
        a1 = __builtin_bit_cast(v8s, HF[i0 + 16]);
      } else {
        a0 = __builtin_bit_cast(v8s, uc_ld16((const u16*)(HF + i0)));
        a1 = __builtin_bit_cast(v8s, uc_ld16((const u16*)(HF + i0 + 16)));
      }
      o0 = __builtin_amdgcn_mfma_f32_16x16x32_bf16(a0, bfrag, o0, 0, 0, 0);
      o1 = __builtin_amdgcn_mfma_f32_16x16x32_bf16(a1, bfrag, o1, 0, 0, 0);
    }
    float bO = WhyB[colO];
#pragma unroll
    for (int r2 = 0; r2 < 4; ++r2) {
      int row = (w << 5) + (l4 << 2) + r2;
      out[row * O_ + colO] = o0[r2] + bO;
      out[(row + 16) * O_ + colO] = o1[r2] + bO;
    }
  }
}

// ------------------------------------------------------------- launch ----
extern "C" void kernel_launch(void* const* d_in, const int* in_sizes, int n_in,
                              void* d_out, int out_size, void* d_ws, size_t ws_size,
                              hipStream_t stream) {
  const float* x    = (const float*)d_in[0];
  const float* Wxf  = (const float*)d_in[1];
  const float* bf_  = (const float*)d_in[2];
  const float* Whf  = (const float*)d_in[3];
  const float* Wxi  = (const float*)d_in[4];
  const float* bi_  = (const float*)d_in[5];
  const float* Whi  = (const float*)d_in[6];
  const float* Wxg  = (const float*)d_in[7];
  const float* bg_  = (const float*)d_in[8];
  const float* Whg  = (const float*)d_in[9];
  const float* Wxo  = (const float*)d_in[10];
  const float* bo_  = (const float*)d_in[11];
  const float* Who  = (const float*)d_in[12];
  const float* Why  = (const float*)d_in[13];
  const float* Whyb = (const float*)d_in[14];

  char* ws = (char*)d_ws;
  u16*   xtp  = (u16*)(ws);                    // xA: 33,554,432 B
  u16*   Wcp  = (u16*)(ws + 33554432);         // WcF: 12,582,912 B
  float* bcp  = (float*)(ws + 46137344);       //     16,384 B
  u16*   WhyT = (u16*)(ws + 46153728);         //  1,048,576 B
  u32*   barp = (u32*)(ws + 47202304);         //      1,024 B
  u16*   hbuf = (u16*)(ws + 47203328);         // hA: rot 257*256KB else 512KB
  float* outp = (float*)d_out;

  const size_t need_rot = 47203328ull + 257ull * 262144ull;  // ~114.6 MB
  int rot = (ws_size >= need_rot) ? 1 : 0;

  lstm_prep<<<dim3(1024), dim3(256), 0, stream>>>(
      x, Whf, Whi, Whg, Who, Wxf, Wxi, Wxg, Wxo,
      bf_, bi_, bg_, bo_, Why, xtp, Wcp, bcp, WhyT, hbuf, barp);

  lstm_seq<<<dim3(256), dim3(256), 0, stream>>>(
      xtp, Wcp, bcp, hbuf, WhyT, Whyb, outp, barp, rot);
}